// Round 1
// 1073.790 us; speedup vs baseline: 1.0256x; 1.0256x over previous
//
#include <hip/hip_runtime.h>

#define NROWS 524288
#define DIM 256
#define NSEG 8192
#define SPB 8            // segments per block in gemm_pool_kernel
#define SEGS3 8          // segments per block in proj_kernel

typedef __attribute__((ext_vector_type(8))) short bf16x8;
typedef __attribute__((ext_vector_type(4))) float f32x4;

__device__ __forceinline__ short f2bf(float f) {
  union { float f; unsigned u; } a; a.f = f;
  unsigned r = a.u + 0x7fffu + ((a.u >> 16) & 1u);   // RNE
  return (short)(r >> 16);
}

// K1: seg_start[s] = lower_bound(batch_index, s), s in [0, NSEG]
__global__ void seg_start_kernel(const int* __restrict__ bi, int* __restrict__ ss) {
  int s = blockIdx.x * blockDim.x + threadIdx.x;
  if (s > NSEG) return;
  int lo = 0, hi = NROWS;
  while (lo < hi) { int mid = (lo + hi) >> 1; if (bi[mid] < s) lo = mid + 1; else hi = mid; }
  ss[s] = lo;
}

// K2: fused h = x@W1^T (bf16 MFMA) + segmented mean/max entirely in registers.
// - double-buffered x staging, ONE barrier per 16-row chunk (was 2)
// - no hT LDS round-trip: per-lane partial sum/max over the quad's 4 C-rows,
//   cross-quad shfl_xor combine only at segment flush (~8 flushes/block)
// - uniform segment walk on ss[] (no bi[] reads, no serial 16-iter loop)
__global__ __launch_bounds__(256, 2) void gemm_pool_kernel(
    const float* __restrict__ x, const float* __restrict__ W1,
    const float* __restrict__ b1, const int* __restrict__ ss,
    float* __restrict__ xpool) {
  __shared__ short x_lds[2][16 * 264];   // 2 x (16 rows x 256 k bf16, padded stride)

  const int tid  = threadIdx.x;
  const int wave = tid >> 6, lane = tid & 63;
  const int quad = lane >> 4, l16 = lane & 15;

  const int s0i = blockIdx.x * SPB;
  const int r0 = ss[s0i];
  const int r1 = ss[s0i + SPB];
  if (r0 >= r1) return;               // block-uniform: all 8 segments empty

  // W1 B-fragment register cache: this wave's 64 output cols, all K=256.
  // B frag layout: n = lane&15 (output col), k = ks*32 + quad*8 + j
  bf16x8 bfr[4][8];
  #pragma unroll
  for (int tt = 0; tt < 4; ++tt) {
    const int col = wave * 64 + tt * 16 + l16;
    #pragma unroll
    for (int ks = 0; ks < 8; ++ks) {
      const float* p = W1 + (size_t)col * DIM + ks * 32 + quad * 8;
      f32x4 w0 = *(const f32x4*)p;
      f32x4 w1 = *(const f32x4*)(p + 4);
      bf16x8 f;
      f[0]=f2bf(w0[0]); f[1]=f2bf(w0[1]); f[2]=f2bf(w0[2]); f[3]=f2bf(w0[3]);
      f[4]=f2bf(w1[0]); f[5]=f2bf(w1[1]); f[6]=f2bf(w1[2]); f[7]=f2bf(w1[3]);
      bfr[tt][ks] = f;
    }
  }
  // bias for the flush store lane->col mapping: col = wave*64 + quad*16 + l16
  const float b1f = b1[wave * 64 + quad * 16 + l16];

  const int srow = tid >> 4;
  const int scol = (tid & 15) * 16;

  // prologue: stage chunk 0 into buffer 0
  {
    const int row = r0 + srow;
    if (row < r1) {
      const float* xp = x + (size_t)row * DIM + scol;
      f32x4 v0 = *(const f32x4*)xp;
      f32x4 v1 = *(const f32x4*)(xp + 4);
      f32x4 v2 = *(const f32x4*)(xp + 8);
      f32x4 v3 = *(const f32x4*)(xp + 12);
      bf16x8 a0, a1;
      a0[0]=f2bf(v0[0]); a0[1]=f2bf(v0[1]); a0[2]=f2bf(v0[2]); a0[3]=f2bf(v0[3]);
      a0[4]=f2bf(v1[0]); a0[5]=f2bf(v1[1]); a0[6]=f2bf(v1[2]); a0[7]=f2bf(v1[3]);
      a1[0]=f2bf(v2[0]); a1[1]=f2bf(v2[1]); a1[2]=f2bf(v2[2]); a1[3]=f2bf(v2[3]);
      a1[4]=f2bf(v3[0]); a1[5]=f2bf(v3[1]); a1[6]=f2bf(v3[2]); a1[7]=f2bf(v3[3]);
      *(bf16x8*)&x_lds[0][srow * 264 + scol] = a0;
      *(bf16x8*)&x_lds[0][srow * 264 + scol + 8] = a1;
    }
  }
  __syncthreads();

  // uniform segment-walk state (scalar; no dynamic-indexed local arrays)
  int idx = 0;
  int seg_lo = r0;
  int seg_hi = ss[s0i + 1];
  while (seg_hi == seg_lo) { ++idx; seg_lo = seg_hi; seg_hi = ss[s0i + idx + 1]; }

  float ssum[4] = {0.f, 0.f, 0.f, 0.f};
  float smax[4] = {-3.0e38f, -3.0e38f, -3.0e38f, -3.0e38f};

  const int nch = (r1 - r0 + 15) >> 4;
  for (int c = 0; c < nch; ++c) {
    const int base = r0 + c * 16;
    int nr = r1 - base; if (nr > 16) nr = 16;

    // T14 async-stage split: issue next chunk's global loads BEFORE compute
    f32x4 v0, v1, v2, v3;
    const int prow = base + 16 + srow;
    const bool pf = (prow < r1);
    if (pf) {
      const float* xp = x + (size_t)prow * DIM + scol;
      v0 = *(const f32x4*)xp;
      v1 = *(const f32x4*)(xp + 4);
      v2 = *(const f32x4*)(xp + 8);
      v3 = *(const f32x4*)(xp + 12);
    }

    // MFMA: 16 rows x 256 cols, K=256. A frag: m = lane&15, k = ks*32 + quad*8 + j
    const short* xb = x_lds[c & 1];
    f32x4 acc[4] = {{0.f,0.f,0.f,0.f},{0.f,0.f,0.f,0.f},{0.f,0.f,0.f,0.f},{0.f,0.f,0.f,0.f}};
    #pragma unroll
    for (int ks = 0; ks < 8; ++ks) {
      bf16x8 a = *(const bf16x8*)&xb[l16 * 264 + ks * 32 + quad * 8];
      acc[0] = __builtin_amdgcn_mfma_f32_16x16x32_bf16(a, bfr[0][ks], acc[0], 0, 0, 0);
      acc[1] = __builtin_amdgcn_mfma_f32_16x16x32_bf16(a, bfr[1][ks], acc[1], 0, 0, 0);
      acc[2] = __builtin_amdgcn_mfma_f32_16x16x32_bf16(a, bfr[2][ks], acc[2], 0, 0, 0);
      acc[3] = __builtin_amdgcn_mfma_f32_16x16x32_bf16(a, bfr[3][ks], acc[3], 0, 0, 0);
    }

    // segmented reduce. C layout: col = lane&15, row = quad*4 + reg.
    // Per-lane partials over this quad's rows; combine cross-quad only at flush.
    int r = 0;
    while (r < nr) {
      int e = seg_hi - base; if (e > nr) e = nr;       // run [r, e), uniform
      if (r == 0 && e == 16) {                         // fast path: whole chunk in-segment
        #pragma unroll
        for (int tt = 0; tt < 4; ++tt) {
          ssum[tt] += (acc[tt][0] + acc[tt][1]) + (acc[tt][2] + acc[tt][3]);
          smax[tt] = fmaxf(smax[tt], fmaxf(fmaxf(acc[tt][0], acc[tt][1]),
                                           fmaxf(acc[tt][2], acc[tt][3])));
        }
      } else {
        #pragma unroll
        for (int tt = 0; tt < 4; ++tt) {
          #pragma unroll
          for (int j = 0; j < 4; ++j) {
            const int row = (quad << 2) + j;
            const bool in = (row >= r) && (row < e);
            ssum[tt] += in ? acc[tt][j] : 0.f;
            smax[tt] = in ? fmaxf(smax[tt], acc[tt][j]) : smax[tt];
          }
        }
      }
      if (base + e == seg_hi) {
        // flush segment (s0i + idx): cross-quad combine, quad-selects its tt
        float c0 = ssum[0], c1 = ssum[1], c2 = ssum[2], c3 = ssum[3];
        c0 += __shfl_xor(c0, 16); c0 += __shfl_xor(c0, 32);
        c1 += __shfl_xor(c1, 16); c1 += __shfl_xor(c1, 32);
        c2 += __shfl_xor(c2, 16); c2 += __shfl_xor(c2, 32);
        c3 += __shfl_xor(c3, 16); c3 += __shfl_xor(c3, 32);
        float m0 = smax[0], m1 = smax[1], m2 = smax[2], m3 = smax[3];
        m0 = fmaxf(m0, __shfl_xor(m0, 16)); m0 = fmaxf(m0, __shfl_xor(m0, 32));
        m1 = fmaxf(m1, __shfl_xor(m1, 16)); m1 = fmaxf(m1, __shfl_xor(m1, 32));
        m2 = fmaxf(m2, __shfl_xor(m2, 16)); m2 = fmaxf(m2, __shfl_xor(m2, 32));
        m3 = fmaxf(m3, __shfl_xor(m3, 16)); m3 = fmaxf(m3, __shfl_xor(m3, 32));
        const float fs = (quad & 2) ? ((quad & 1) ? c3 : c2) : ((quad & 1) ? c1 : c0);
        const float fm = (quad & 2) ? ((quad & 1) ? m3 : m2) : ((quad & 1) ? m1 : m0);
        const float inv = 1.f / (float)(seg_hi - seg_lo);
        const int col = wave * 64 + quad * 16 + l16;
        xpool[(size_t)(s0i + idx) * 512 + col]       = fs * inv + b1f;
        xpool[(size_t)(s0i + idx) * 512 + 256 + col] = fm + b1f;
        ssum[0]=0.f; ssum[1]=0.f; ssum[2]=0.f; ssum[3]=0.f;
        smax[0]=-3.0e38f; smax[1]=-3.0e38f; smax[2]=-3.0e38f; smax[3]=-3.0e38f;
        if (base + e < r1) {   // advance to next non-empty segment
          do { ++idx; seg_lo = seg_hi; seg_hi = ss[s0i + idx + 1]; } while (seg_hi == seg_lo);
        }
      }
      r = e;
    }

    // late half of the stage: convert + LDS-write the prefetched chunk
    if (pf) {
      bf16x8 a0, a1;
      a0[0]=f2bf(v0[0]); a0[1]=f2bf(v0[1]); a0[2]=f2bf(v0[2]); a0[3]=f2bf(v0[3]);
      a0[4]=f2bf(v1[0]); a0[5]=f2bf(v1[1]); a0[6]=f2bf(v1[2]); a0[7]=f2bf(v1[3]);
      a1[0]=f2bf(v2[0]); a1[1]=f2bf(v2[1]); a1[2]=f2bf(v2[2]); a1[3]=f2bf(v2[3]);
      a1[4]=f2bf(v3[0]); a1[5]=f2bf(v3[1]); a1[6]=f2bf(v3[2]); a1[7]=f2bf(v3[3]);
      short* dst = &x_lds[(c + 1) & 1][srow * 264 + scol];
      *(bf16x8*)dst = a0;
      *(bf16x8*)(dst + 8) = a1;
    }
    __syncthreads();   // single barrier per chunk (double-buffered)
  }
}

// K3: out_pool[s][j] = sum_k xpool[s][k] * Wp[j][k] + bp[j]
// SEGS3=8 -> grid 1024 (>=4 blocks/CU) to hide LDS/L2 latency.
__global__ __launch_bounds__(256) void proj_kernel(
    const float* __restrict__ xpool, const float* __restrict__ Wp,
    const float* __restrict__ bp, float* __restrict__ out_pool) {
  __shared__ float xp_lds[SEGS3 * 512];
  const int tid = threadIdx.x;
  const size_t s0 = (size_t)blockIdx.x * SEGS3;
  for (int i = tid; i < SEGS3 * 128; i += 256)
    *(f32x4*)&xp_lds[i * 4] = *(const f32x4*)&xpool[s0 * 512 + (size_t)i * 4];
  __syncthreads();
  float acc[SEGS3];
  #pragma unroll
  for (int s = 0; s < SEGS3; ++s) acc[s] = 0.f;
  for (int k0 = 0; k0 < 512; k0 += 4) {
    f32x4 wp = *(const f32x4*)&Wp[(size_t)tid * 512 + k0];
    #pragma unroll
    for (int s = 0; s < SEGS3; ++s) {
      f32x4 xv = *(const f32x4*)&xp_lds[s * 512 + k0];   // same-addr broadcast
      acc[s] += xv[0]*wp[0] + xv[1]*wp[1] + xv[2]*wp[2] + xv[3]*wp[3];
    }
  }
  const float b = bp[tid];
  #pragma unroll
  for (int s = 0; s < SEGS3; ++s)
    out_pool[(s0 + s) * 256 + tid] = acc[s] + b;
}

// K4: out[n][:] = out_pool[batch_index[n]][:]   (write-bound, float4)
__global__ __launch_bounds__(256) void gather_kernel(const int* __restrict__ bi,
                              const float* __restrict__ out_pool,
                              float* __restrict__ out) {
  const size_t idx = (size_t)blockIdx.x * blockDim.x + threadIdx.x; // float4 units
  const int n  = (int)(idx >> 6);    // 64 float4 per row
  const int c4 = (int)(idx & 63);
  const int s = bi[n];
  f32x4 v = *(const f32x4*)&out_pool[(size_t)s * 256 + c4 * 4];
  *(f32x4*)&out[(size_t)n * 256 + (size_t)c4 * 4] = v;
}

extern "C" void kernel_launch(void* const* d_in, const int* in_sizes, int n_in,
                              void* d_out, int out_size, void* d_ws, size_t ws_size,
                              hipStream_t stream) {
  const float* x  = (const float*)d_in[0];
  const int*   bi = (const int*)d_in[1];
  const float* W1 = (const float*)d_in[2];
  const float* b1 = (const float*)d_in[3];
  const float* Wp = (const float*)d_in[4];
  const float* bp = (const float*)d_in[5];
  float* out = (float*)d_out;

  char* ws = (char*)d_ws;
  int*   ss       = (int*)ws;                                   // 8193 ints
  float* xpool    = (float*)(ws + 64 * 1024);                   // [8192][512] f32 = 16 MiB
  float* out_pool = (float*)(ws + 64 * 1024 + (size_t)NSEG * 512 * 4); // [8192][256] = 8 MiB

  seg_start_kernel<<<(NSEG + 256) / 256, 256, 0, stream>>>(bi, ss);
  gemm_pool_kernel<<<NSEG / SPB, 256, 0, stream>>>(x, W1, b1, ss, xpool);
  proj_kernel<<<NSEG / SEGS3, 256, 0, stream>>>(xpool, Wp, bp, out_pool);
  gather_kernel<<<(size_t)NROWS * (DIM / 4) / 256, 256, 0, stream>>>(bi, out_pool, out);
}

// Round 2
// 1060.790 us; speedup vs baseline: 1.0382x; 1.0123x over previous
//
#include <hip/hip_runtime.h>

#define NROWS 524288
#define DIM 256
#define NSEG 8192
#define SPB 8            // segments per block in gemm_pool_kernel
#define SEGS3 8          // segments per block in proj_kernel

typedef __attribute__((ext_vector_type(8))) short bf16x8;
typedef __attribute__((ext_vector_type(4))) float f32x4;

__device__ __forceinline__ short f2bf(float f) {
  union { float f; unsigned u; } a; a.f = f;
  unsigned r = a.u + 0x7fffu + ((a.u >> 16) & 1u);   // RNE
  return (short)(r >> 16);
}

// K1: seg_start[s] = lower_bound(batch_index, s), s in [0, NSEG]
__global__ void seg_start_kernel(const int* __restrict__ bi, int* __restrict__ ss) {
  int s = blockIdx.x * blockDim.x + threadIdx.x;
  if (s > NSEG) return;
  int lo = 0, hi = NROWS;
  while (lo < hi) { int mid = (lo + hi) >> 1; if (bi[mid] < s) lo = mid + 1; else hi = mid; }
  ss[s] = lo;
}

// K2: fused h = x@W1^T (bf16 MFMA) + segmented mean/max entirely in registers.
// - 2-deep prefetch pipeline: two NAMED reg sets (A/B), loop unrolled x2 so every
//   chunk's global loads have a full chunk-time in flight before their ds_write use
//   (compiler emits counted vmcnt via per-register deps)
// - non-temporal x loads (read-once stream, don't evict W1/ss)
// - per-lane partial sum/max in MFMA C layout; cross-quad shfl only at segment flush
__global__ __launch_bounds__(256, 2) void gemm_pool_kernel(
    const float* __restrict__ x, const float* __restrict__ W1,
    const float* __restrict__ b1, const int* __restrict__ ss,
    float* __restrict__ xpool) {
  __shared__ short x_lds[2][16 * 264];   // 2 x (16 rows x 256 k bf16, padded stride)

  const int tid  = threadIdx.x;
  const int wave = tid >> 6, lane = tid & 63;
  const int quad = lane >> 4, l16 = lane & 15;

  const int s0i = blockIdx.x * SPB;
  const int r0 = ss[s0i];
  const int r1 = ss[s0i + SPB];
  if (r0 >= r1) return;               // block-uniform: all 8 segments empty

  // W1 B-fragment register cache: this wave's 64 output cols, all K=256.
  // B frag layout: n = lane&15 (output col), k = ks*32 + quad*8 + j
  bf16x8 bfr[4][8];
  #pragma unroll
  for (int tt = 0; tt < 4; ++tt) {
    const int col = wave * 64 + tt * 16 + l16;
    #pragma unroll
    for (int ks = 0; ks < 8; ++ks) {
      const float* p = W1 + (size_t)col * DIM + ks * 32 + quad * 8;
      f32x4 w0 = *(const f32x4*)p;
      f32x4 w1 = *(const f32x4*)(p + 4);
      bf16x8 f;
      f[0]=f2bf(w0[0]); f[1]=f2bf(w0[1]); f[2]=f2bf(w0[2]); f[3]=f2bf(w0[3]);
      f[4]=f2bf(w1[0]); f[5]=f2bf(w1[1]); f[6]=f2bf(w1[2]); f[7]=f2bf(w1[3]);
      bfr[tt][ks] = f;
    }
  }
  const float b1f = b1[wave * 64 + quad * 16 + l16];

  const int srow = tid >> 4;
  const int scol = (tid & 15) * 16;

  // segment-walk state
  int idx = 0;
  int seg_lo = r0;
  int seg_hi = ss[s0i + 1];
  while (seg_hi == seg_lo) { ++idx; seg_lo = seg_hi; seg_hi = ss[s0i + idx + 1]; }

  float ssum[4] = {0.f, 0.f, 0.f, 0.f};
  float smax[4] = {-3.0e38f, -3.0e38f, -3.0e38f, -3.0e38f};
  f32x4 acc[4];

  auto issue_loads = [&](int prow, f32x4& v0, f32x4& v1, f32x4& v2, f32x4& v3) -> bool {
    bool pf = (prow < r1);
    if (pf) {
      const f32x4* xp = (const f32x4*)(x + (size_t)prow * DIM + scol);
      v0 = __builtin_nontemporal_load(xp);
      v1 = __builtin_nontemporal_load(xp + 1);
      v2 = __builtin_nontemporal_load(xp + 2);
      v3 = __builtin_nontemporal_load(xp + 3);
    }
    return pf;
  };
  auto stage_write = [&](int buf, const f32x4& v0, const f32x4& v1,
                         const f32x4& v2, const f32x4& v3) {
    bf16x8 a0, a1;
    a0[0]=f2bf(v0[0]); a0[1]=f2bf(v0[1]); a0[2]=f2bf(v0[2]); a0[3]=f2bf(v0[3]);
    a0[4]=f2bf(v1[0]); a0[5]=f2bf(v1[1]); a0[6]=f2bf(v1[2]); a0[7]=f2bf(v1[3]);
    a1[0]=f2bf(v2[0]); a1[1]=f2bf(v2[1]); a1[2]=f2bf(v2[2]); a1[3]=f2bf(v2[3]);
    a1[4]=f2bf(v3[0]); a1[5]=f2bf(v3[1]); a1[6]=f2bf(v3[2]); a1[7]=f2bf(v3[3]);
    short* dst = &x_lds[buf][srow * 264 + scol];
    *(bf16x8*)dst = a0;
    *(bf16x8*)(dst + 8) = a1;
  };
  auto compute_chunk = [&](int c) {
    const int base = r0 + c * 16;
    int nr = r1 - base; if (nr > 16) nr = 16;
    const short* xb = x_lds[c & 1];
    acc[0] = (f32x4){0.f,0.f,0.f,0.f}; acc[1] = (f32x4){0.f,0.f,0.f,0.f};
    acc[2] = (f32x4){0.f,0.f,0.f,0.f}; acc[3] = (f32x4){0.f,0.f,0.f,0.f};
    #pragma unroll
    for (int ks = 0; ks < 8; ++ks) {
      bf16x8 a = *(const bf16x8*)&xb[l16 * 264 + ks * 32 + quad * 8];
      acc[0] = __builtin_amdgcn_mfma_f32_16x16x32_bf16(a, bfr[0][ks], acc[0], 0, 0, 0);
      acc[1] = __builtin_amdgcn_mfma_f32_16x16x32_bf16(a, bfr[1][ks], acc[1], 0, 0, 0);
      acc[2] = __builtin_amdgcn_mfma_f32_16x16x32_bf16(a, bfr[2][ks], acc[2], 0, 0, 0);
      acc[3] = __builtin_amdgcn_mfma_f32_16x16x32_bf16(a, bfr[3][ks], acc[3], 0, 0, 0);
    }
    // segmented reduce. C layout: col = lane&15, row = quad*4 + reg.
    int r = 0;
    while (r < nr) {
      int e = seg_hi - base; if (e > nr) e = nr;       // run [r, e), uniform
      if (r == 0 && e == 16) {                         // whole chunk in-segment
        #pragma unroll
        for (int tt = 0; tt < 4; ++tt) {
          ssum[tt] += (acc[tt][0] + acc[tt][1]) + (acc[tt][2] + acc[tt][3]);
          smax[tt] = fmaxf(smax[tt], fmaxf(fmaxf(acc[tt][0], acc[tt][1]),
                                           fmaxf(acc[tt][2], acc[tt][3])));
        }
      } else {
        #pragma unroll
        for (int tt = 0; tt < 4; ++tt) {
          #pragma unroll
          for (int j = 0; j < 4; ++j) {
            const int row = (quad << 2) + j;
            const bool in = (row >= r) && (row < e);
            ssum[tt] += in ? acc[tt][j] : 0.f;
            smax[tt] = in ? fmaxf(smax[tt], acc[tt][j]) : smax[tt];
          }
        }
      }
      if (base + e == seg_hi) {
        // flush segment (s0i + idx): cross-quad combine, quad selects its tt
        float c0 = ssum[0], c1 = ssum[1], c2 = ssum[2], c3 = ssum[3];
        c0 += __shfl_xor(c0, 16); c0 += __shfl_xor(c0, 32);
        c1 += __shfl_xor(c1, 16); c1 += __shfl_xor(c1, 32);
        c2 += __shfl_xor(c2, 16); c2 += __shfl_xor(c2, 32);
        c3 += __shfl_xor(c3, 16); c3 += __shfl_xor(c3, 32);
        float m0 = smax[0], m1 = smax[1], m2 = smax[2], m3 = smax[3];
        m0 = fmaxf(m0, __shfl_xor(m0, 16)); m0 = fmaxf(m0, __shfl_xor(m0, 32));
        m1 = fmaxf(m1, __shfl_xor(m1, 16)); m1 = fmaxf(m1, __shfl_xor(m1, 32));
        m2 = fmaxf(m2, __shfl_xor(m2, 16)); m2 = fmaxf(m2, __shfl_xor(m2, 32));
        m3 = fmaxf(m3, __shfl_xor(m3, 16)); m3 = fmaxf(m3, __shfl_xor(m3, 32));
        const float fs = (quad & 2) ? ((quad & 1) ? c3 : c2) : ((quad & 1) ? c1 : c0);
        const float fm = (quad & 2) ? ((quad & 1) ? m3 : m2) : ((quad & 1) ? m1 : m0);
        const float inv = 1.f / (float)(seg_hi - seg_lo);
        const int col = wave * 64 + quad * 16 + l16;
        xpool[(size_t)(s0i + idx) * 512 + col]       = fs * inv + b1f;
        xpool[(size_t)(s0i + idx) * 512 + 256 + col] = fm + b1f;
        ssum[0]=0.f; ssum[1]=0.f; ssum[2]=0.f; ssum[3]=0.f;
        smax[0]=-3.0e38f; smax[1]=-3.0e38f; smax[2]=-3.0e38f; smax[3]=-3.0e38f;
        if (base + e < r1) {
          do { ++idx; seg_lo = seg_hi; seg_hi = ss[s0i + idx + 1]; } while (seg_hi == seg_lo);
        }
      }
      r = e;
    }
  };

  const int nch = (r1 - r0 + 15) >> 4;

  // prologue: chunk0 -> LDS0 directly (B set transient), issue chunk1 -> A
  f32x4 a0v, a1v, a2v, a3v, b0v, b1v_, b2v, b3v;
  bool pfa = false, pfb = false;
  {
    bool p0 = issue_loads(r0 + srow, b0v, b1v_, b2v, b3v);
    if (p0) stage_write(0, b0v, b1v_, b2v, b3v);
  }
  pfa = issue_loads(r0 + 16 + srow, a0v, a1v, a2v, a3v);
  __syncthreads();

  // steady state: A holds odd chunks, B holds even chunks (2-deep pipeline)
  for (int c = 0; c < nch; c += 2) {
    // even body: compute c, write A(c+1) -> LDS1, issue c+2 -> B
    pfb = issue_loads(r0 + (c + 2) * 16 + srow, b0v, b1v_, b2v, b3v);
    compute_chunk(c);
    if (pfa) stage_write((c + 1) & 1, a0v, a1v, a2v, a3v);
    __syncthreads();
    if (c + 1 >= nch) break;
    // odd body: compute c+1, write B(c+2) -> LDS0, issue c+3 -> A
    pfa = issue_loads(r0 + (c + 3) * 16 + srow, a0v, a1v, a2v, a3v);
    compute_chunk(c + 1);
    if (pfb) stage_write(c & 1, b0v, b1v_, b2v, b3v);
    __syncthreads();
  }
}

// K3: out_pool[s][j] = sum_k xpool[s][k] * Wp[j][k] + bp[j]
__global__ __launch_bounds__(256) void proj_kernel(
    const float* __restrict__ xpool, const float* __restrict__ Wp,
    const float* __restrict__ bp, float* __restrict__ out_pool) {
  __shared__ float xp_lds[SEGS3 * 512];
  const int tid = threadIdx.x;
  const size_t s0 = (size_t)blockIdx.x * SEGS3;
  for (int i = tid; i < SEGS3 * 128; i += 256)
    *(f32x4*)&xp_lds[i * 4] = *(const f32x4*)&xpool[s0 * 512 + (size_t)i * 4];
  __syncthreads();
  float acc[SEGS3];
  #pragma unroll
  for (int s = 0; s < SEGS3; ++s) acc[s] = 0.f;
  for (int k0 = 0; k0 < 512; k0 += 4) {
    f32x4 wp = *(const f32x4*)&Wp[(size_t)tid * 512 + k0];
    #pragma unroll
    for (int s = 0; s < SEGS3; ++s) {
      f32x4 xv = *(const f32x4*)&xp_lds[s * 512 + k0];   // same-addr broadcast
      acc[s] += xv[0]*wp[0] + xv[1]*wp[1] + xv[2]*wp[2] + xv[3]*wp[3];
    }
  }
  const float b = bp[tid];
  #pragma unroll
  for (int s = 0; s < SEGS3; ++s)
    out_pool[(s0 + s) * 256 + tid] = acc[s] + b;
}

// K4: out[n][:] = out_pool[batch_index[n]][:]
// batch_index is SORTED -> one block per segment: read the segment's out_pool row
// ONCE into registers, then pure streaming non-temporal writes (no gather reads).
__global__ __launch_bounds__(256) void gather_kernel(
    const int* __restrict__ ss, const float* __restrict__ out_pool,
    float* __restrict__ out) {
  const int s = blockIdx.x;
  const int lo = ss[s], hi = ss[s + 1];
  if (lo >= hi) return;
  const int tid = threadIdx.x;
  const int rofs = tid >> 6;          // 0..3: 4 rows per iteration
  const int c4 = tid & 63;            // float4 column within the row
  const f32x4 v = *(const f32x4*)&out_pool[(size_t)s * 256 + (size_t)c4 * 4];
  for (int n = lo + rofs; n < hi; n += 4)
    __builtin_nontemporal_store(v, (f32x4*)&out[(size_t)n * 256 + (size_t)c4 * 4]);
}

extern "C" void kernel_launch(void* const* d_in, const int* in_sizes, int n_in,
                              void* d_out, int out_size, void* d_ws, size_t ws_size,
                              hipStream_t stream) {
  const float* x  = (const float*)d_in[0];
  const int*   bi = (const int*)d_in[1];
  const float* W1 = (const float*)d_in[2];
  const float* b1 = (const float*)d_in[3];
  const float* Wp = (const float*)d_in[4];
  const float* bp = (const float*)d_in[5];
  float* out = (float*)d_out;

  char* ws = (char*)d_ws;
  int*   ss       = (int*)ws;                                   // 8193 ints
  float* xpool    = (float*)(ws + 64 * 1024);                   // [8192][512] f32 = 16 MiB
  float* out_pool = (float*)(ws + 64 * 1024 + (size_t)NSEG * 512 * 4); // [8192][256] = 8 MiB

  seg_start_kernel<<<(NSEG + 256) / 256, 256, 0, stream>>>(bi, ss);
  gemm_pool_kernel<<<NSEG / SPB, 256, 0, stream>>>(x, W1, b1, ss, xpool);
  proj_kernel<<<NSEG / SEGS3, 256, 0, stream>>>(xpool, Wp, bp, out_pool);
  gather_kernel<<<NSEG, 256, 0, stream>>>(ss, out_pool, out);
}

// Round 3
// 1037.026 us; speedup vs baseline: 1.0620x; 1.0229x over previous
//
#include <hip/hip_runtime.h>

#define NROWS 524288
#define DIM 256
#define NSEG 8192
#define SPB 8            // segments per block in gemm_pool_kernel
#define SEGS3 8          // segments per block in proj_gather_kernel

typedef __attribute__((ext_vector_type(8))) short bf16x8;
typedef __attribute__((ext_vector_type(4))) float f32x4;

__device__ __forceinline__ short f2bf(float f) {
  union { float f; unsigned u; } a; a.f = f;
  unsigned r = a.u + 0x7fffu + ((a.u >> 16) & 1u);   // RNE
  return (short)(r >> 16);
}

// LDS-only barrier (HK/m201 pattern): order ds ops across the barrier WITHOUT
// draining vmcnt -- keeps the 2-deep global prefetch in flight. __syncthreads()
// would emit s_waitcnt vmcnt(0) and kill the pipeline (m97 ceiling mechanism).
__device__ __forceinline__ void lds_barrier() {
  asm volatile("s_waitcnt lgkmcnt(0)" ::: "memory");
  __builtin_amdgcn_sched_barrier(0);
  __builtin_amdgcn_s_barrier();
  __builtin_amdgcn_sched_barrier(0);
}

// K1: seg_start[s] = lower_bound(batch_index, s), s in [0, NSEG]
__global__ void seg_start_kernel(const int* __restrict__ bi, int* __restrict__ ss) {
  int s = blockIdx.x * blockDim.x + threadIdx.x;
  if (s > NSEG) return;
  int lo = 0, hi = NROWS;
  while (lo < hi) { int mid = (lo + hi) >> 1; if (bi[mid] < s) lo = mid + 1; else hi = mid; }
  ss[s] = lo;
}

// K2: fused h = x@W1^T (bf16 MFMA) + segmented mean/max entirely in registers.
// 2-deep prefetch (named A/B reg sets, x2-unrolled loop) + LDS-only barriers.
__global__ __launch_bounds__(256, 2) void gemm_pool_kernel(
    const float* __restrict__ x, const float* __restrict__ W1,
    const float* __restrict__ b1, const int* __restrict__ ss,
    float* __restrict__ xpool) {
  __shared__ short x_lds[2][16 * 264];   // 2 x (16 rows x 256 k bf16, padded stride)

  const int tid  = threadIdx.x;
  const int wave = tid >> 6, lane = tid & 63;
  const int quad = lane >> 4, l16 = lane & 15;

  const int s0i = blockIdx.x * SPB;
  const int r0 = ss[s0i];
  const int r1 = ss[s0i + SPB];
  if (r0 >= r1) return;               // block-uniform: all 8 segments empty

  // W1 B-fragment register cache: this wave's 64 output cols, all K=256.
  // B frag layout: n = lane&15 (output col), k = ks*32 + quad*8 + j
  bf16x8 bfr[4][8];
  #pragma unroll
  for (int tt = 0; tt < 4; ++tt) {
    const int col = wave * 64 + tt * 16 + l16;
    #pragma unroll
    for (int ks = 0; ks < 8; ++ks) {
      const float* p = W1 + (size_t)col * DIM + ks * 32 + quad * 8;
      f32x4 w0 = *(const f32x4*)p;
      f32x4 w1 = *(const f32x4*)(p + 4);
      bf16x8 f;
      f[0]=f2bf(w0[0]); f[1]=f2bf(w0[1]); f[2]=f2bf(w0[2]); f[3]=f2bf(w0[3]);
      f[4]=f2bf(w1[0]); f[5]=f2bf(w1[1]); f[6]=f2bf(w1[2]); f[7]=f2bf(w1[3]);
      bfr[tt][ks] = f;
    }
  }
  const float b1f = b1[wave * 64 + quad * 16 + l16];

  const int srow = tid >> 4;
  const int scol = (tid & 15) * 16;

  // segment-walk state
  int idx = 0;
  int seg_lo = r0;
  int seg_hi = ss[s0i + 1];
  while (seg_hi == seg_lo) { ++idx; seg_lo = seg_hi; seg_hi = ss[s0i + idx + 1]; }

  float ssum[4] = {0.f, 0.f, 0.f, 0.f};
  float smax[4] = {-3.0e38f, -3.0e38f, -3.0e38f, -3.0e38f};
  f32x4 acc[4];

  auto issue_loads = [&](int prow, f32x4& v0, f32x4& v1, f32x4& v2, f32x4& v3) -> bool {
    bool pf = (prow < r1);
    if (pf) {
      const f32x4* xp = (const f32x4*)(x + (size_t)prow * DIM + scol);
      v0 = __builtin_nontemporal_load(xp);
      v1 = __builtin_nontemporal_load(xp + 1);
      v2 = __builtin_nontemporal_load(xp + 2);
      v3 = __builtin_nontemporal_load(xp + 3);
    }
    return pf;
  };
  auto stage_write = [&](int buf, const f32x4& v0, const f32x4& v1,
                         const f32x4& v2, const f32x4& v3) {
    bf16x8 a0, a1;
    a0[0]=f2bf(v0[0]); a0[1]=f2bf(v0[1]); a0[2]=f2bf(v0[2]); a0[3]=f2bf(v0[3]);
    a0[4]=f2bf(v1[0]); a0[5]=f2bf(v1[1]); a0[6]=f2bf(v1[2]); a0[7]=f2bf(v1[3]);
    a1[0]=f2bf(v2[0]); a1[1]=f2bf(v2[1]); a1[2]=f2bf(v2[2]); a1[3]=f2bf(v2[3]);
    a1[4]=f2bf(v3[0]); a1[5]=f2bf(v3[1]); a1[6]=f2bf(v3[2]); a1[7]=f2bf(v3[3]);
    short* dst = &x_lds[buf][srow * 264 + scol];
    *(bf16x8*)dst = a0;
    *(bf16x8*)(dst + 8) = a1;
  };
  auto compute_chunk = [&](int c) {
    const int base = r0 + c * 16;
    int nr = r1 - base; if (nr > 16) nr = 16;
    const short* xb = x_lds[c & 1];
    acc[0] = (f32x4){0.f,0.f,0.f,0.f}; acc[1] = (f32x4){0.f,0.f,0.f,0.f};
    acc[2] = (f32x4){0.f,0.f,0.f,0.f}; acc[3] = (f32x4){0.f,0.f,0.f,0.f};
    #pragma unroll
    for (int ks = 0; ks < 8; ++ks) {
      bf16x8 a = *(const bf16x8*)&xb[l16 * 264 + ks * 32 + quad * 8];
      acc[0] = __builtin_amdgcn_mfma_f32_16x16x32_bf16(a, bfr[0][ks], acc[0], 0, 0, 0);
      acc[1] = __builtin_amdgcn_mfma_f32_16x16x32_bf16(a, bfr[1][ks], acc[1], 0, 0, 0);
      acc[2] = __builtin_amdgcn_mfma_f32_16x16x32_bf16(a, bfr[2][ks], acc[2], 0, 0, 0);
      acc[3] = __builtin_amdgcn_mfma_f32_16x16x32_bf16(a, bfr[3][ks], acc[3], 0, 0, 0);
    }
    // segmented reduce. C layout: col = lane&15, row = quad*4 + reg.
    int r = 0;
    while (r < nr) {
      int e = seg_hi - base; if (e > nr) e = nr;       // run [r, e), uniform
      if (r == 0 && e == 16) {                         // whole chunk in-segment
        #pragma unroll
        for (int tt = 0; tt < 4; ++tt) {
          ssum[tt] += (acc[tt][0] + acc[tt][1]) + (acc[tt][2] + acc[tt][3]);
          smax[tt] = fmaxf(smax[tt], fmaxf(fmaxf(acc[tt][0], acc[tt][1]),
                                           fmaxf(acc[tt][2], acc[tt][3])));
        }
      } else {
        #pragma unroll
        for (int tt = 0; tt < 4; ++tt) {
          #pragma unroll
          for (int j = 0; j < 4; ++j) {
            const int row = (quad << 2) + j;
            const bool in = (row >= r) && (row < e);
            ssum[tt] += in ? acc[tt][j] : 0.f;
            smax[tt] = in ? fmaxf(smax[tt], acc[tt][j]) : smax[tt];
          }
        }
      }
      if (base + e == seg_hi) {
        // flush segment (s0i + idx): cross-quad combine, quad selects its tt
        float c0 = ssum[0], c1 = ssum[1], c2 = ssum[2], c3 = ssum[3];
        c0 += __shfl_xor(c0, 16); c0 += __shfl_xor(c0, 32);
        c1 += __shfl_xor(c1, 16); c1 += __shfl_xor(c1, 32);
        c2 += __shfl_xor(c2, 16); c2 += __shfl_xor(c2, 32);
        c3 += __shfl_xor(c3, 16); c3 += __shfl_xor(c3, 32);
        float m0 = smax[0], m1 = smax[1], m2 = smax[2], m3 = smax[3];
        m0 = fmaxf(m0, __shfl_xor(m0, 16)); m0 = fmaxf(m0, __shfl_xor(m0, 32));
        m1 = fmaxf(m1, __shfl_xor(m1, 16)); m1 = fmaxf(m1, __shfl_xor(m1, 32));
        m2 = fmaxf(m2, __shfl_xor(m2, 16)); m2 = fmaxf(m2, __shfl_xor(m2, 32));
        m3 = fmaxf(m3, __shfl_xor(m3, 16)); m3 = fmaxf(m3, __shfl_xor(m3, 32));
        const float fs = (quad & 2) ? ((quad & 1) ? c3 : c2) : ((quad & 1) ? c1 : c0);
        const float fm = (quad & 2) ? ((quad & 1) ? m3 : m2) : ((quad & 1) ? m1 : m0);
        const float inv = 1.f / (float)(seg_hi - seg_lo);
        const int col = wave * 64 + quad * 16 + l16;
        xpool[(size_t)(s0i + idx) * 512 + col]       = fs * inv + b1f;
        xpool[(size_t)(s0i + idx) * 512 + 256 + col] = fm + b1f;
        ssum[0]=0.f; ssum[1]=0.f; ssum[2]=0.f; ssum[3]=0.f;
        smax[0]=-3.0e38f; smax[1]=-3.0e38f; smax[2]=-3.0e38f; smax[3]=-3.0e38f;
        if (base + e < r1) {
          do { ++idx; seg_lo = seg_hi; seg_hi = ss[s0i + idx + 1]; } while (seg_hi == seg_lo);
        }
      }
      r = e;
    }
  };

  const int nch = (r1 - r0 + 15) >> 4;

  // prologue: chunk0 -> LDS0 directly (B set transient), issue chunk1 -> A
  f32x4 a0v, a1v, a2v, a3v, b0v, b1v_, b2v, b3v;
  bool pfa = false, pfb = false;
  {
    bool p0 = issue_loads(r0 + srow, b0v, b1v_, b2v, b3v);
    if (p0) stage_write(0, b0v, b1v_, b2v, b3v);
  }
  pfa = issue_loads(r0 + 16 + srow, a0v, a1v, a2v, a3v);
  lds_barrier();

  // steady state: A holds odd chunks, B holds even chunks (2-deep pipeline)
  for (int c = 0; c < nch; c += 2) {
    // even body: compute c, write A(c+1) -> LDS1, issue c+2 -> B
    pfb = issue_loads(r0 + (c + 2) * 16 + srow, b0v, b1v_, b2v, b3v);
    compute_chunk(c);
    if (pfa) stage_write((c + 1) & 1, a0v, a1v, a2v, a3v);
    lds_barrier();
    if (c + 1 >= nch) break;
    // odd body: compute c+1, write B(c+2) -> LDS0, issue c+3 -> A
    pfa = issue_loads(r0 + (c + 3) * 16 + srow, a0v, a1v, a2v, a3v);
    compute_chunk(c + 1);
    if (pfb) stage_write(c & 1, b0v, b1v_, b2v, b3v);
    lds_barrier();
  }
}

// K3 (fused proj + gather): for each segment s, compute
//   row[j] = sum_k xpool[s][k]*Wp[j][k] + bp[j]   (thread j = tid owns one col)
// then stream the row to out[n][:] for every n in [ss[s], ss[s+1]) (sorted bi ->
// contiguous rows, pure NT writes). xpool is read with wave-UNIFORM addresses ->
// compiler scalarizes to s_load (no VALU/LDS/VMEM slot cost); Wp rows are
// per-thread vector loads served by L2.
__global__ __launch_bounds__(256) void proj_gather_kernel(
    const float* __restrict__ xpool, const float* __restrict__ Wp,
    const float* __restrict__ bp, const int* __restrict__ ss,
    float* __restrict__ out) {
  const int tid = threadIdx.x;
  const int s0 = blockIdx.x * SEGS3;

  f32x4 acc4[SEGS3];
  #pragma unroll
  for (int s = 0; s < SEGS3; ++s) acc4[s] = (f32x4){0.f, 0.f, 0.f, 0.f};

  const float* wrow = Wp + (size_t)tid * 512;
  for (int k0 = 0; k0 < 512; k0 += 8) {
    f32x4 wp0 = *(const f32x4*)(wrow + k0);
    f32x4 wp1 = *(const f32x4*)(wrow + k0 + 4);
    #pragma unroll
    for (int s = 0; s < SEGS3; ++s) {
      f32x4 xv0 = *(const f32x4*)&xpool[(size_t)(s0 + s) * 512 + k0];     // uniform
      f32x4 xv1 = *(const f32x4*)&xpool[(size_t)(s0 + s) * 512 + k0 + 4]; // uniform
      acc4[s] += xv0 * wp0 + xv1 * wp1;
    }
  }
  const float b = bp[tid];
  #pragma unroll
  for (int s = 0; s < SEGS3; ++s) {
    const float v = (acc4[s][0] + acc4[s][1]) + (acc4[s][2] + acc4[s][3]) + b;
    const int lo = ss[s0 + s], hi = ss[s0 + s + 1];
    for (int n = lo; n < hi; ++n)
      __builtin_nontemporal_store(v, &out[(size_t)n * 256 + tid]);
  }
}

extern "C" void kernel_launch(void* const* d_in, const int* in_sizes, int n_in,
                              void* d_out, int out_size, void* d_ws, size_t ws_size,
                              hipStream_t stream) {
  const float* x  = (const float*)d_in[0];
  const int*   bi = (const int*)d_in[1];
  const float* W1 = (const float*)d_in[2];
  const float* b1 = (const float*)d_in[3];
  const float* Wp = (const float*)d_in[4];
  const float* bp = (const float*)d_in[5];
  float* out = (float*)d_out;

  char* ws = (char*)d_ws;
  int*   ss    = (int*)ws;                  // 8193 ints
  float* xpool = (float*)(ws + 64 * 1024);  // [8192][512] f32 = 16 MiB

  seg_start_kernel<<<(NSEG + 256) / 256, 256, 0, stream>>>(bi, ss);
  gemm_pool_kernel<<<NSEG / SPB, 256, 0, stream>>>(x, W1, b1, ss, xpool);
  proj_gather_kernel<<<NSEG / SEGS3, 256, 0, stream>>>(xpool, Wp, bp, ss, out);
}